// Round 1
// baseline (191.382 us; speedup 1.0000x reference)
//
#include <hip/hip_runtime.h>

// HPSS: harmonic/percussive separation.
// S: (B=2, C=1, F=1025, T=2048) float32, non-negative.
// harm = median_31 along T (zero-padded), perc = median_31 along F.
// mask_h = h^2/(h^2+p^2), mask_p = p^2/(h^2+p^2)   (softmask Z cancels)
// out = concat(S*mask_h, S*mask_p) flat.

#define DIM_T 2048
#define DIM_F 1025
#define KWIN 31
#define HALF 15

__device__ __forceinline__ float median31(float (&w)[KWIN]) {
    // partial selection sort: after pass i, w[i] holds the (i+1)-th smallest.
    // all indices compile-time -> stays in VGPRs.
#pragma unroll
    for (int i = 0; i < 16; ++i) {
#pragma unroll
        for (int j = i + 1; j < KWIN; ++j) {
            float a = w[i], b = w[j];
            w[i] = fminf(a, b);
            w[j] = fmaxf(a, b);
        }
    }
    return w[15];
}

__global__ __launch_bounds__(256) void hpss_kernel(const float* __restrict__ S,
                                                   float* __restrict__ outH,
                                                   float* __restrict__ outP) {
    const int t = blockIdx.x * 256 + threadIdx.x;   // T = 2048 = 8*256, no tail
    const int f = blockIdx.y;
    const int b = blockIdx.z;

    const size_t rowBase = ((size_t)b * DIM_F + (size_t)f) * DIM_T;
    const size_t idx = rowBase + (size_t)t;
    const float* __restrict__ row = S + rowBase;        // index by t
    const float* __restrict__ col = S + (size_t)b * DIM_F * DIM_T + (size_t)t; // index by f*T

    float w[KWIN];

    // ---- harmonic: window along T ----
#pragma unroll
    for (int d = 0; d < KWIN; ++d) {
        int tt = t + d - HALF;
        float v = 0.0f;
        if (tt >= 0 && tt < DIM_T) v = row[tt];
        w[d] = v;
    }
    const float harm = median31(w);

    // ---- percussive: window along F ----
#pragma unroll
    for (int d = 0; d < KWIN; ++d) {
        int ff = f + d - HALF;
        float v = 0.0f;
        if (ff >= 0 && ff < DIM_F) v = col[(size_t)ff * DIM_T];
        w[d] = v;
    }
    const float perc = median31(w);

    const float s  = row[t];
    const float h2 = harm * harm;
    const float p2 = perc * perc;
    const float denom = h2 + p2;      // 0/0 -> NaN matches reference semantics
    outH[idx] = s * (h2 / denom);
    outP[idx] = s * (p2 / denom);
}

extern "C" void kernel_launch(void* const* d_in, const int* in_sizes, int n_in,
                              void* d_out, int out_size, void* d_ws, size_t ws_size,
                              hipStream_t stream) {
    const float* S = (const float*)d_in[0];
    float* outH = (float*)d_out;
    float* outP = (float*)d_out + (size_t)2 * DIM_F * DIM_T;  // B*C*F*T elements

    dim3 grid(DIM_T / 256, DIM_F, 2);
    dim3 block(256);
    hpss_kernel<<<grid, block, 0, stream>>>(S, outH, outP);
}

// Round 2
// 151.962 us; speedup vs baseline: 1.2594x; 1.2594x over previous
//
#include <hip/hip_runtime.h>

// HPSS: S (2,1,1025,2048) fp32 non-negative.
// harm = median_31 along T (zero pad), perc = median_31 along F.
// mask_h = h^2/(h^2+p^2); out = [S*mask_h, S*mask_p] concatenated.
//
// Median via forgetful selection: buffer of 17 candidates; the true median
// (rank 16 of 31) can never be the min or max of the buffer, since at most
// d + unseen <= 14 < 15 elements can lie below (above) it outside the buffer.
// Each stage: position min at b[0] / max at b[c-1] (2c-3 compare-exchanges),
// replace min with next element, drop max (shrink c). 255 CEs total vs 360
// for partial selection sort, and live set 17 (no spills) vs 31.

#define DIM_T 2048
#define DIM_F 1025
#define KWIN 31
#define HALF 15

__device__ __forceinline__ void ce(float& a, float& b) {
    const float mn = fminf(a, b);
    b = fmaxf(a, b);
    a = mn;
}

template <typename Ld>
__device__ __forceinline__ float median31(const Ld& ld) {
    float b[17];
#pragma unroll
    for (int i = 0; i < 17; ++i) b[i] = ld(i);
#pragma unroll
    for (int c = 17; c >= 4; --c) {
        // min -> b[0]
#pragma unroll
        for (int j = 1; j < c; ++j) ce(b[0], b[j]);
        // max -> b[c-1]
#pragma unroll
        for (int j = 1; j < c - 1; ++j) ce(b[j], b[c - 1]);
        b[0] = ld(34 - c);   // consume next element; b[c-1] (max) is dropped
    }
    return __builtin_amdgcn_fmed3f(b[0], b[1], b[2]);  // median of last 3
}

__global__ __launch_bounds__(256) void hpss_kernel(const float* __restrict__ S,
                                                   float* __restrict__ outH,
                                                   float* __restrict__ outP) {
    const int t = blockIdx.x * 256 + threadIdx.x;   // 2048 = 8 * 256
    const int f = blockIdx.y;
    const int bz = blockIdx.z;

    const size_t planeBase = (size_t)bz * DIM_F * DIM_T;
    const size_t rowBase   = planeBase + (size_t)f * DIM_T;
    const float* __restrict__ row = S + rowBase;        // indexed by t
    const float* __restrict__ col = S + planeBase + t;  // indexed by f*T

    // block-uniform edge classification (t-range is block-uniform; f is blockIdx.y)
    const bool interior = (blockIdx.x != 0) & (blockIdx.x != gridDim.x - 1) &
                          (f >= HALF) & (f < DIM_F - HALF);

    float harm, perc;
    if (interior) {
        harm = median31([&](int d) { return row[t + d - HALF]; });
        perc = median31([&](int d) { return col[(size_t)(f + d - HALF) * DIM_T]; });
    } else {
        harm = median31([&](int d) {
            const int tt = t + d - HALF;
            return ((unsigned)tt < (unsigned)DIM_T) ? row[tt] : 0.0f;
        });
        perc = median31([&](int d) {
            const int ff = f + d - HALF;
            return ((unsigned)ff < (unsigned)DIM_F) ? col[(size_t)ff * DIM_T] : 0.0f;
        });
    }

    const float s  = row[t];
    const float h2 = harm * harm;
    const float p2 = perc * perc;
    const float denom = h2 + p2;          // 0/0 -> NaN matches reference
    outH[rowBase + t] = s * (h2 / denom);
    outP[rowBase + t] = s * (p2 / denom);
}

extern "C" void kernel_launch(void* const* d_in, const int* in_sizes, int n_in,
                              void* d_out, int out_size, void* d_ws, size_t ws_size,
                              hipStream_t stream) {
    const float* S = (const float*)d_in[0];
    float* outH = (float*)d_out;
    float* outP = (float*)d_out + (size_t)2 * DIM_F * DIM_T;

    dim3 grid(DIM_T / 256, DIM_F, 2);
    dim3 block(256);
    hpss_kernel<<<grid, block, 0, stream>>>(S, outH, outP);
}